// Round 1
// baseline (68467.004 us; speedup 1.0000x reference)
//
#include <hip/hip_runtime.h>
#include <hip/hip_bf16.h>
#include <math.h>

#define NNODES 100000
#define FIN 500
#define HIDDIM 64
#define NCLS 40
#define KORD 10

// ---------------- degree / dis ----------------
__global__ __launch_bounds__(256) void deg_kernel(const int* __restrict__ src,
                                                  float* __restrict__ deg, int E) {
  int e = blockIdx.x * 256 + threadIdx.x;
  if (e < E) atomicAdd(&deg[src[e]], 1.0f);
}

__global__ __launch_bounds__(256) void dis_kernel(const float* __restrict__ deg,
                                                  float* __restrict__ dis, int n) {
  int i = blockIdx.x * 256 + threadIdx.x;
  if (i < n) {
    float d = deg[i];
    dis[i] = d > 0.f ? 1.0f / sqrtf(d) : 0.f;
  }
}

// ---------------- polynomial coefficients from temp ----------------
// out = sum_j C(K,j)/2^K * relu(temp[j]) * (I-A)^j (I+A)^{K-j} h
//     = sum_m g[m] * A^m h
// g[m] = sum_j s_j * T[j][m],  T[j][m] = coeff of x^m in (1-x)^j (1+x)^{K-j}
// All intermediates are dyadic rationals with numerators < 2^24 -> exact in f32.
__global__ void coeff_kernel(const float* __restrict__ temp, float* __restrict__ g) {
  if (threadIdx.x != 0 || blockIdx.x != 0) return;
  float C[KORD + 1][KORD + 1];
  for (int n = 0; n <= KORD; ++n)
    for (int k = 0; k <= KORD; ++k) C[n][k] = 0.f;
  for (int n = 0; n <= KORD; ++n) {
    C[n][0] = 1.f;
    for (int k = 1; k <= n; ++k) C[n][k] = C[n - 1][k - 1] + C[n - 1][k];
  }
  float s[KORD + 1];
  for (int j = 0; j <= KORD; ++j) {
    float th = temp[j] > 0.f ? temp[j] : 0.f;
    s[j] = C[KORD][j] * (1.0f / 1024.0f) * th;
  }
  for (int m = 0; m <= KORD; ++m) {
    float acc = 0.f;
    for (int j = 0; j <= KORD; ++j) {
      float T = 0.f;
      for (int a = 0; a <= m; ++a) {
        int b = m - a;
        if (a <= j && b <= KORD - j)
          T += ((a & 1) ? -1.f : 1.f) * C[j][a] * C[KORD - j][b];
      }
      acc += s[j] * T;
    }
    g[m] = acc;
  }
}

// ---------------- fused 2-layer MLP: u = relu(x@W1+b1)@W2+b2 ----------------
#define BM 64
#define BK 20  // 500 = 25*20
__global__ __launch_bounds__(256) void mlp_kernel(
    const float* __restrict__ x, const float* __restrict__ W1,
    const float* __restrict__ b1, const float* __restrict__ W2,
    const float* __restrict__ b2, float* __restrict__ u, int n) {
  __shared__ float xs[BM][BK];
  __shared__ float wsm[BK][HIDDIM];
  __shared__ float hs[BM][HIDDIM + 1];  // +1 pad: avoid bank conflicts in GEMM2
  __shared__ float w2s[HIDDIM][NCLS];

  int block_row = blockIdx.x * BM;
  int t = threadIdx.x;
  int ty = t >> 4, tx = t & 15;

  float acc[4][4] = {};
  for (int k0 = 0; k0 < FIN; k0 += BK) {
    for (int i = t; i < BM * BK; i += 256) {
      int r = i / BK, c = i % BK;
      int gr = block_row + r;
      xs[r][c] = (gr < n) ? x[(size_t)gr * FIN + k0 + c] : 0.f;
    }
    for (int i = t; i < BK * HIDDIM; i += 256) {
      int r = i >> 6, c = i & 63;
      wsm[r][c] = W1[(size_t)(k0 + r) * HIDDIM + c];
    }
    __syncthreads();
#pragma unroll
    for (int k = 0; k < BK; ++k) {
      float a[4], b[4];
#pragma unroll
      for (int i = 0; i < 4; ++i) a[i] = xs[ty + 16 * i][k];
#pragma unroll
      for (int j = 0; j < 4; ++j) b[j] = wsm[k][tx + 16 * j];
#pragma unroll
      for (int i = 0; i < 4; ++i)
#pragma unroll
        for (int j = 0; j < 4; ++j) acc[i][j] += a[i] * b[j];
    }
    __syncthreads();
  }
  // relu + b1 -> hs
#pragma unroll
  for (int i = 0; i < 4; ++i)
#pragma unroll
    for (int j = 0; j < 4; ++j) {
      int r = ty + 16 * i, c = tx + 16 * j;
      float v = acc[i][j] + b1[c];
      hs[r][c] = v > 0.f ? v : 0.f;
    }
  for (int i = t; i < HIDDIM * NCLS; i += 256) w2s[i / NCLS][i % NCLS] = W2[i];
  __syncthreads();

  // GEMM2: 64 rows x 40 cols; thread -> (row, 10-col group)
  int row = t >> 2, cg = (t & 3) * 10;
  float o[10] = {};
  for (int k = 0; k < HIDDIM; ++k) {
    float a = hs[row][k];
#pragma unroll
    for (int j = 0; j < 10; ++j) o[j] += a * w2s[k][cg + j];
  }
  int gr = block_row + row;
  if (gr < n) {
    float* urow = u + (size_t)gr * NCLS + cg;
#pragma unroll
    for (int j = 0; j < 10; ++j) urow[j] = o[j] + b2[cg + j];
  }
}

// ---------------- out = g0*u (out lives in d_out second half) ----------------
__global__ __launch_bounds__(256) void init_kernel(const float* __restrict__ u,
                                                   const float* __restrict__ g,
                                                   float* __restrict__ out, int n) {
  int i = blockIdx.x * 256 + threadIdx.x;  // float4 groups, n*10 total
  if (i >= n * 10) return;
  float g0 = g[0];
  float4 q = ((const float4*)u)[i];
  q.x *= g0; q.y *= g0; q.z *= g0; q.w *= g0;
  ((float4*)out)[i] = q;
}

// ---------------- edge scatter: v[dst] += dis[src]*u[src] ----------------
__global__ __launch_bounds__(256) void scatter_kernel(
    const int* __restrict__ src, const int* __restrict__ dst,
    const float* __restrict__ dis, const float* __restrict__ u,
    float* __restrict__ v, int E) {
  int e = blockIdx.x * 256 + threadIdx.x;
  if (e >= E) return;
  int s = src[e], d = dst[e];
  float w = dis[s];
  const float4* us = (const float4*)(u + (size_t)s * NCLS);
  float* vd = v + (size_t)d * NCLS;
#pragma unroll
  for (int f = 0; f < 10; ++f) {
    float4 q = us[f];
    atomicAdd(vd + 4 * f + 0, w * q.x);
    atomicAdd(vd + 4 * f + 1, w * q.y);
    atomicAdd(vd + 4 * f + 2, w * q.z);
    atomicAdd(vd + 4 * f + 3, w * q.w);
  }
}

// ---------------- u = dis*v ; out += g[m]*u ----------------
__global__ __launch_bounds__(256) void finish_kernel(
    const float* __restrict__ dis, const float* __restrict__ g, int m,
    const float* __restrict__ v, float* __restrict__ u, float* __restrict__ out,
    int n) {
  int i = blockIdx.x * 256 + threadIdx.x;  // float4 groups, n*10 total
  if (i >= n * 10) return;
  float ds = dis[i / 10];
  float gm = g[m];
  float4 q = ((const float4*)v)[i];
  q.x *= ds; q.y *= ds; q.z *= ds; q.w *= ds;
  ((float4*)u)[i] = q;
  float4 o = ((float4*)out)[i];
  o.x += gm * q.x; o.y += gm * q.y; o.z += gm * q.z; o.w += gm * q.w;
  ((float4*)out)[i] = o;
}

// ---------------- log_softmax: one 64-lane wave per row ----------------
__global__ __launch_bounds__(256) void lsm_kernel(const float* __restrict__ out,
                                                  float* __restrict__ lsm, int n) {
  int wid = blockIdx.x * 4 + (threadIdx.x >> 6);
  int lane = threadIdx.x & 63;
  if (wid >= n) return;
  float xv = (lane < NCLS) ? out[(size_t)wid * NCLS + lane] : -INFINITY;
  float mx = xv;
#pragma unroll
  for (int off = 32; off; off >>= 1) mx = fmaxf(mx, __shfl_xor(mx, off));
  float e = (lane < NCLS) ? expf(xv - mx) : 0.f;
  float sum = e;
#pragma unroll
  for (int off = 32; off; off >>= 1) sum += __shfl_xor(sum, off);
  float lse = logf(sum);
  if (lane < NCLS) lsm[(size_t)wid * NCLS + lane] = xv - mx - lse;
}

extern "C" void kernel_launch(void* const* d_in, const int* in_sizes, int n_in,
                              void* d_out, int out_size, void* d_ws, size_t ws_size,
                              hipStream_t stream) {
  (void)n_in; (void)out_size; (void)ws_size;
  const float* x = (const float*)d_in[0];
  const int* ei = (const int*)d_in[1];
  const float* W1 = (const float*)d_in[2];
  const float* b1 = (const float*)d_in[3];
  const float* W2 = (const float*)d_in[4];
  const float* b2 = (const float*)d_in[5];
  const float* temp = (const float*)d_in[6];
  int E = in_sizes[1] / 2;
  const int* src = ei;
  const int* dst = ei + E;
  int n = NNODES;

  float* ws = (float*)d_ws;
  float* u = ws;                   // n*40
  float* v = ws + 4000000;         // n*40
  float* deg = ws + 8000000;       // n
  float* dis = ws + 8100000;       // n
  float* g = ws + 8200000;         // K+1

  float* lsm = (float*)d_out;            // n*40
  float* out = (float*)d_out + 4000000;  // n*40 (accumulator, final output 1)

  hipMemsetAsync(deg, 0, n * sizeof(float), stream);
  deg_kernel<<<(E + 255) / 256, 256, 0, stream>>>(src, deg, E);
  dis_kernel<<<(n + 255) / 256, 256, 0, stream>>>(deg, dis, n);
  coeff_kernel<<<1, 64, 0, stream>>>(temp, g);
  mlp_kernel<<<(n + BM - 1) / BM, 256, 0, stream>>>(x, W1, b1, W2, b2, u, n);
  init_kernel<<<(n * 10 + 255) / 256, 256, 0, stream>>>(u, g, out, n);
  for (int m = 1; m <= KORD; ++m) {
    hipMemsetAsync(v, 0, (size_t)n * NCLS * sizeof(float), stream);
    scatter_kernel<<<(E + 255) / 256, 256, 0, stream>>>(src, dst, dis, u, v, E);
    finish_kernel<<<(n * 10 + 255) / 256, 256, 0, stream>>>(dis, g, m, v, u, out, n);
  }
  lsm_kernel<<<(n + 3) / 4, 256, 0, stream>>>(out, lsm, n);
}

// Round 4
// 447.300 us; speedup vs baseline: 153.0672x; 153.0672x over previous
//
#include <hip/hip_runtime.h>
#include <hip/hip_bf16.h>
#include <math.h>

#define NNODES 100000
#define FIN 500
#define HIDDIM 64
#define NCLS 40
#define KORD 10

// ---------------- polynomial coefficients + need-flags from temp ----------------
// out = sum_j C(K,j)/2^K * relu(temp[j]) * (I-A)^j (I+A)^{K-j} h = sum_m g[m] A^m h
// g[m] = sum_j s_j * T[j][m], T[j][m] = coeff of x^m in (1-x)^j (1+x)^{K-j}.
// All intermediates are integers/1024 with numerators < 2^24 -> exact in f32.
// flags[m] = 1 iff any g[j] != 0 for j >= m  (i.e. SpMV step m is still needed).
__global__ void coeff_kernel(const float* __restrict__ temp, float* __restrict__ g,
                             int* __restrict__ flags) {
  if (threadIdx.x != 0 || blockIdx.x != 0) return;
  float C[KORD + 1][KORD + 1];
  for (int n = 0; n <= KORD; ++n)
    for (int k = 0; k <= KORD; ++k) C[n][k] = 0.f;
  for (int n = 0; n <= KORD; ++n) {
    C[n][0] = 1.f;
    for (int k = 1; k <= n; ++k) C[n][k] = C[n - 1][k - 1] + C[n - 1][k];
  }
  float s[KORD + 1];
  for (int j = 0; j <= KORD; ++j) {
    float th = temp[j] > 0.f ? temp[j] : 0.f;
    s[j] = C[KORD][j] * (1.0f / 1024.0f) * th;
  }
  for (int m = 0; m <= KORD; ++m) {
    float acc = 0.f;
    for (int j = 0; j <= KORD; ++j) {
      float T = 0.f;
      for (int a = 0; a <= m; ++a) {
        int b = m - a;
        if (a <= j && b <= KORD - j)
          T += ((a & 1) ? -1.f : 1.f) * C[j][a] * C[KORD - j][b];
      }
      acc += s[j] * T;
    }
    g[m] = acc;
  }
  int any = 0;
  flags[0] = 1;
  for (int m = KORD; m >= 1; --m) {
    if (g[m] != 0.f) any = 1;
    flags[m] = any;
  }
}

// ---------------- counts: out-degree at src + in-degree at dst ----------------
__global__ __launch_bounds__(256) void cnt_kernel(const int* __restrict__ src,
                                                  const int* __restrict__ dst,
                                                  int* __restrict__ deg_i,
                                                  int* __restrict__ cnt_dst,
                                                  const int* __restrict__ flags, int E) {
  if (flags[1] == 0) return;
  int e = blockIdx.x * 256 + threadIdx.x;
  if (e < E) {
    atomicAdd(&deg_i[src[e]], 1);
    atomicAdd(&cnt_dst[dst[e]], 1);
  }
}

__global__ __launch_bounds__(256) void dis_kernel(const int* __restrict__ deg_i,
                                                  float* __restrict__ dis,
                                                  const int* __restrict__ flags, int n) {
  if (flags[1] == 0) return;
  int i = blockIdx.x * 256 + threadIdx.x;
  if (i < n) {
    int d = deg_i[i];
    dis[i] = d > 0 ? 1.0f / sqrtf((float)d) : 0.f;
  }
}

// ---------------- exclusive prefix sum of cnt_dst -> rowptr[0..n] ----------------
__global__ __launch_bounds__(1024) void scan_kernel(const int* __restrict__ cnt,
                                                    int* __restrict__ rowptr,
                                                    const int* __restrict__ flags) {
  if (flags[1] == 0) return;
  __shared__ int part[1024];
  int t = threadIdx.x;
  const int chunk = (NNODES + 1023) / 1024;  // 98
  int lo = t * chunk, hi = lo + chunk;
  if (hi > NNODES) hi = NNODES;
  int s = 0;
  for (int i = lo; i < hi; ++i) s += cnt[i];
  part[t] = s;
  __syncthreads();
  for (int off = 1; off < 1024; off <<= 1) {
    int v = (t >= off) ? part[t - off] : 0;
    __syncthreads();
    part[t] += v;
    __syncthreads();
  }
  int run = (t > 0) ? part[t - 1] : 0;
  for (int i = lo; i < hi; ++i) {
    rowptr[i] = run;
    run += cnt[i];
  }
  if (t == 1023) rowptr[NNODES] = run;
}

// ---------------- CSR fill (dst-major): col[pos] = src ----------------
__global__ __launch_bounds__(256) void fill_kernel(const int* __restrict__ src,
                                                   const int* __restrict__ dst,
                                                   const int* __restrict__ rowptr,
                                                   int* __restrict__ tmpc,
                                                   int* __restrict__ col,
                                                   const int* __restrict__ flags, int E) {
  if (flags[1] == 0) return;
  int e = blockIdx.x * 256 + threadIdx.x;
  if (e >= E) return;
  int d = dst[e];
  int pos = rowptr[d] + atomicAdd(&tmpc[d], 1);
  col[pos] = src[e];
}

// ---------------- fused 2-layer MLP: u = relu(x@W1+b1)@W2+b2 ----------------
#define BM 64
#define BK 20
__global__ __launch_bounds__(256) void mlp_kernel(
    const float* __restrict__ x, const float* __restrict__ W1,
    const float* __restrict__ b1, const float* __restrict__ W2,
    const float* __restrict__ b2, float* __restrict__ u, int n) {
  __shared__ float xs[BM][BK];
  __shared__ float wsm[BK][HIDDIM];
  __shared__ float hs[BM][HIDDIM + 1];
  __shared__ float w2s[HIDDIM][NCLS];

  int block_row = blockIdx.x * BM;
  int t = threadIdx.x;
  int ty = t >> 4, tx = t & 15;

  float acc[4][4] = {};
  for (int k0 = 0; k0 < FIN; k0 += BK) {
    for (int i = t; i < BM * BK; i += 256) {
      int r = i / BK, c = i % BK;
      int gr = block_row + r;
      xs[r][c] = (gr < n) ? x[(size_t)gr * FIN + k0 + c] : 0.f;
    }
    for (int i = t; i < BK * HIDDIM; i += 256) {
      int r = i >> 6, c = i & 63;
      wsm[r][c] = W1[(size_t)(k0 + r) * HIDDIM + c];
    }
    __syncthreads();
#pragma unroll
    for (int k = 0; k < BK; ++k) {
      float a[4], b[4];
#pragma unroll
      for (int i = 0; i < 4; ++i) a[i] = xs[ty + 16 * i][k];
#pragma unroll
      for (int j = 0; j < 4; ++j) b[j] = wsm[k][tx + 16 * j];
#pragma unroll
      for (int i = 0; i < 4; ++i)
#pragma unroll
        for (int j = 0; j < 4; ++j) acc[i][j] += a[i] * b[j];
    }
    __syncthreads();
  }
#pragma unroll
  for (int i = 0; i < 4; ++i)
#pragma unroll
    for (int j = 0; j < 4; ++j) {
      int r = ty + 16 * i, c = tx + 16 * j;
      float v = acc[i][j] + b1[c];
      hs[r][c] = v > 0.f ? v : 0.f;
    }
  for (int i = t; i < HIDDIM * NCLS; i += 256) w2s[i / NCLS][i % NCLS] = W2[i];
  __syncthreads();

  int row = t >> 2, cg = (t & 3) * 10;
  float o[10] = {};
  for (int k = 0; k < HIDDIM; ++k) {
    float a = hs[row][k];
#pragma unroll
    for (int j = 0; j < 10; ++j) o[j] += a * w2s[k][cg + j];
  }
  int gr = block_row + row;
  if (gr < n) {
    float* urow = u + (size_t)gr * NCLS + cg;
#pragma unroll
    for (int j = 0; j < 10; ++j) urow[j] = o[j] + b2[cg + j];
  }
}

// ---------------- out = g0*u ----------------
__global__ __launch_bounds__(256) void init_kernel(const float* __restrict__ u,
                                                   const float* __restrict__ g,
                                                   float* __restrict__ out, int n) {
  int i = blockIdx.x * 256 + threadIdx.x;
  if (i >= n * 10) return;
  float g0 = g[0];
  float4 q = ((const float4*)u)[i];
  q.x *= g0; q.y *= g0; q.z *= g0; q.w *= g0;
  ((float4*)out)[i] = q;
}

// ---------------- SpMV step m: uout = D^-1/2 A D^-1/2 uin ; out += g[m]*uout ----------------
// Wave per node; lanes 0..39 own feature columns. Matches reference associativity:
// sum over edges of (dis[src]*uin[src]), then * dis[dst].
__global__ __launch_bounds__(256) void spmv_kernel(
    const int* __restrict__ col, const int* __restrict__ rowptr,
    const float* __restrict__ dis, const float* __restrict__ uin,
    float* __restrict__ uout, float* __restrict__ out, const float* __restrict__ g,
    const int* __restrict__ flags, int m) {
  if (flags[m] == 0) return;
  int wid = blockIdx.x * 4 + (threadIdx.x >> 6);
  int lane = threadIdx.x & 63;
  if (wid >= NNODES || lane >= NCLS) return;
  int lo = rowptr[wid], hi = rowptr[wid + 1];
  float acc = 0.f;
  for (int e = lo; e < hi; ++e) {
    int s = col[e];
    acc += dis[s] * uin[(size_t)s * NCLS + lane];
  }
  acc *= dis[wid];
  size_t idx = (size_t)wid * NCLS + lane;
  uout[idx] = acc;
  out[idx] += g[m] * acc;
}

// ---------------- log_softmax: one 64-lane wave per row ----------------
__global__ __launch_bounds__(256) void lsm_kernel(const float* __restrict__ out,
                                                  float* __restrict__ lsm, int n) {
  int wid = blockIdx.x * 4 + (threadIdx.x >> 6);
  int lane = threadIdx.x & 63;
  if (wid >= n) return;
  float xv = (lane < NCLS) ? out[(size_t)wid * NCLS + lane] : -INFINITY;
  float mx = xv;
#pragma unroll
  for (int off = 32; off; off >>= 1) mx = fmaxf(mx, __shfl_xor(mx, off));
  float e = (lane < NCLS) ? expf(xv - mx) : 0.f;
  float sum = e;
#pragma unroll
  for (int off = 32; off; off >>= 1) sum += __shfl_xor(sum, off);
  float lse = logf(sum);
  if (lane < NCLS) lsm[(size_t)wid * NCLS + lane] = xv - mx - lse;
}

extern "C" void kernel_launch(void* const* d_in, const int* in_sizes, int n_in,
                              void* d_out, int out_size, void* d_ws, size_t ws_size,
                              hipStream_t stream) {
  (void)n_in; (void)out_size; (void)ws_size;
  const float* x = (const float*)d_in[0];
  const int* ei = (const int*)d_in[1];
  const float* W1 = (const float*)d_in[2];
  const float* b1 = (const float*)d_in[3];
  const float* W2 = (const float*)d_in[4];
  const float* b2 = (const float*)d_in[5];
  const float* temp = (const float*)d_in[6];
  int E = in_sizes[1] / 2;
  const int* src = ei;
  const int* dst = ei + E;
  int n = NNODES;

  // ws layout in 4-byte words; total ~7.8M words = 31.2 MB
  float* ws = (float*)d_ws;
  float* ua = ws;                          // 4,000,000 f32
  int* col = (int*)(ws + 4000000);         // 3,200,000 i32
  int* cnt_dst = (int*)(ws + 7200000);     // 100,000 i32 (memset together with next two)
  int* tmpc = (int*)(ws + 7300000);        // 100,000 i32
  int* deg_i = (int*)(ws + 7400000);       // 100,000 i32
  int* rowptr = (int*)(ws + 7500000);      // 100,001 i32
  float* dis = ws + 7600016;               // 100,000 f32
  float* g = ws + 7700016;                 // 16 f32
  int* flags = (int*)(ws + 7700032);       // 16 i32

  float* lsm = (float*)d_out;            // n*40, also ping-pong scratch during prop
  float* out = (float*)d_out + 4000000;  // n*40 accumulator, final output 1

  (void)hipMemsetAsync(cnt_dst, 0, 300000 * sizeof(int), stream);
  coeff_kernel<<<1, 64, 0, stream>>>(temp, g, flags);
  cnt_kernel<<<(E + 255) / 256, 256, 0, stream>>>(src, dst, deg_i, cnt_dst, flags, E);
  dis_kernel<<<(n + 255) / 256, 256, 0, stream>>>(deg_i, dis, flags, n);
  scan_kernel<<<1, 1024, 0, stream>>>(cnt_dst, rowptr, flags);
  fill_kernel<<<(E + 255) / 256, 256, 0, stream>>>(src, dst, rowptr, tmpc, col, flags, E);
  mlp_kernel<<<(n + BM - 1) / BM, 256, 0, stream>>>(x, W1, b1, W2, b2, ua, n);
  init_kernel<<<(n * 10 + 255) / 256, 256, 0, stream>>>(ua, g, out, n);
  for (int m = 1; m <= KORD; ++m) {
    float* uin = (m & 1) ? ua : lsm;
    float* uout = (m & 1) ? lsm : ua;
    spmv_kernel<<<(n + 3) / 4, 256, 0, stream>>>(col, rowptr, dis, uin, uout, out, g,
                                                 flags, m);
  }
  lsm_kernel<<<(n + 3) / 4, 256, 0, stream>>>(out, lsm, n);
}

// Round 5
// 252.162 us; speedup vs baseline: 271.5197x; 1.7739x over previous
//
#include <hip/hip_runtime.h>
#include <hip/hip_bf16.h>
#include <math.h>

#define NNODES 100000
#define FIN 500
#define KPAD 512
#define HIDDIM 64
#define NCLS 40
#define KORD 10

typedef _Float16 f16;
typedef _Float16 f16x2 __attribute__((ext_vector_type(2)));
typedef _Float16 f16x4 __attribute__((ext_vector_type(4)));
typedef _Float16 f16x8 __attribute__((ext_vector_type(8)));

#if __has_builtin(__builtin_amdgcn_fdot2)
#define DOT2(a, b, c) __builtin_amdgcn_fdot2((a), (b), (c), false)
#else
#define DOT2(a, b, c) \
  fmaf((float)(a)[1], (float)(b)[1], fmaf((float)(a)[0], (float)(b)[0], (c)))
#endif

// ---------------- polynomial coefficients + need-flags from temp ----------------
// out = sum_j C(K,j)/2^K * relu(temp[j]) * (I-A)^j (I+A)^{K-j} h = sum_m g[m] A^m h
// g[m] = sum_j s_j * T[j][m], T[j][m] = coeff of x^m in (1-x)^j (1+x)^{K-j}.
// All intermediates are integers/1024 with numerators < 2^24, exact in f32.
// flags[m] = 1 iff any g[j] != 0 for j >= m  (SpMV step m still needed).
__global__ void coeff_kernel(const float* __restrict__ temp, float* __restrict__ g,
                             int* __restrict__ flags) {
  if (threadIdx.x != 0 || blockIdx.x != 0) return;
  float C[KORD + 1][KORD + 1];
  for (int n = 0; n <= KORD; ++n)
    for (int k = 0; k <= KORD; ++k) C[n][k] = 0.f;
  for (int n = 0; n <= KORD; ++n) {
    C[n][0] = 1.f;
    for (int k = 1; k <= n; ++k) C[n][k] = C[n - 1][k - 1] + C[n - 1][k];
  }
  float s[KORD + 1];
  for (int j = 0; j <= KORD; ++j) {
    float th = temp[j] > 0.f ? temp[j] : 0.f;
    s[j] = C[KORD][j] * (1.0f / 1024.0f) * th;
  }
  for (int m = 0; m <= KORD; ++m) {
    float acc = 0.f;
    for (int j = 0; j <= KORD; ++j) {
      float T = 0.f;
      for (int a = 0; a <= m; ++a) {
        int b = m - a;
        if (a <= j && b <= KORD - j)
          T += ((a & 1) ? -1.f : 1.f) * C[j][a] * C[KORD - j][b];
      }
      acc += s[j] * T;
    }
    g[m] = acc;
  }
  int any = 0;
  flags[0] = 1;
  for (int m = KORD; m >= 1; --m) {
    if (g[m] != 0.f) any = 1;
    flags[m] = any;
  }
}

// ---------------- counts: out-degree at src + in-degree at dst ----------------
__global__ __launch_bounds__(256) void cnt_kernel(const int* __restrict__ src,
                                                  const int* __restrict__ dst,
                                                  int* __restrict__ deg_i,
                                                  int* __restrict__ cnt_dst,
                                                  const int* __restrict__ flags, int E) {
  if (flags[1] == 0) return;
  int e = blockIdx.x * 256 + threadIdx.x;
  if (e < E) {
    atomicAdd(&deg_i[src[e]], 1);
    atomicAdd(&cnt_dst[dst[e]], 1);
  }
}

__global__ __launch_bounds__(256) void dis_kernel(const int* __restrict__ deg_i,
                                                  float* __restrict__ dis,
                                                  const int* __restrict__ flags, int n) {
  if (flags[1] == 0) return;
  int i = blockIdx.x * 256 + threadIdx.x;
  if (i < n) {
    int d = deg_i[i];
    dis[i] = d > 0 ? 1.0f / sqrtf((float)d) : 0.f;
  }
}

// ---------------- exclusive prefix sum of cnt_dst -> rowptr[0..n] ----------------
__global__ __launch_bounds__(1024) void scan_kernel(const int* __restrict__ cnt,
                                                    int* __restrict__ rowptr,
                                                    const int* __restrict__ flags) {
  if (flags[1] == 0) return;
  __shared__ int part[1024];
  int t = threadIdx.x;
  const int chunk = (NNODES + 1023) / 1024;
  int lo = t * chunk, hi = lo + chunk;
  if (hi > NNODES) hi = NNODES;
  int s = 0;
  for (int i = lo; i < hi; ++i) s += cnt[i];
  part[t] = s;
  __syncthreads();
  for (int off = 1; off < 1024; off <<= 1) {
    int v = (t >= off) ? part[t - off] : 0;
    __syncthreads();
    part[t] += v;
    __syncthreads();
  }
  int run = (t > 0) ? part[t - 1] : 0;
  for (int i = lo; i < hi; ++i) {
    rowptr[i] = run;
    run += cnt[i];
  }
  if (t == 1023) rowptr[NNODES] = run;
}

// ---------------- CSR fill (dst-major): col[pos] = src ----------------
__global__ __launch_bounds__(256) void fill_kernel(const int* __restrict__ src,
                                                   const int* __restrict__ dst,
                                                   const int* __restrict__ rowptr,
                                                   int* __restrict__ tmpc,
                                                   int* __restrict__ col,
                                                   const int* __restrict__ flags, int E) {
  if (flags[1] == 0) return;
  int e = blockIdx.x * 256 + threadIdx.x;
  if (e >= E) return;
  int d = dst[e];
  int pos = rowptr[d] + atomicAdd(&tmpc[d], 1);
  col[pos] = src[e];
}

// ---------------- W1 -> transposed, f16, K padded to 512 ----------------
__global__ __launch_bounds__(256) void w1t_kernel(const float* __restrict__ W1,
                                                  f16* __restrict__ w1t) {
  int idx = blockIdx.x * 256 + threadIdx.x;
  if (idx >= HIDDIM * KPAD) return;
  int c = idx >> 9, k = idx & (KPAD - 1);
  float v = (k < FIN) ? W1[(size_t)k * HIDDIM + c] : 0.f;
  w1t[(size_t)c * KPAD + k] = (f16)v;
}

// ---------------- fused MLP: u = relu(x@W1+b1)@W2+b2 ; out = g0*u ----------------
// GEMM1 in f16 inputs / f32 accum via v_dot2_f32_f16, fragments via ds_read_b128.
#define BM 64
#define LDP 72  // f16 row pitch: 144B, 16B-aligned, bank stride 36 words (conflict <= 2-way)
__global__ __launch_bounds__(256) void mlp_kernel(
    const float* __restrict__ x, const f16* __restrict__ w1t,
    const float* __restrict__ b1, const float* __restrict__ W2,
    const float* __restrict__ b2, const float* __restrict__ g,
    float* __restrict__ u, float* __restrict__ out, int n) {
  __shared__ f16 xs[BM][LDP];
  __shared__ f16 bt[HIDDIM][LDP];
  __shared__ float hs[BM][HIDDIM + 1];
  __shared__ float w2s[HIDDIM][NCLS];

  int block_row = blockIdx.x * BM;
  int t = threadIdx.x;
  int ty = t >> 4, tx = t & 15;

  float acc[4][4] = {};
  for (int k0 = 0; k0 < KPAD; k0 += 64) {
    // stage x tile: f32 global -> f16 LDS (zeros beyond FIN or past n)
    for (int i = t; i < BM * 16; i += 256) {
      int r = i >> 4, s = i & 15;
      int k = k0 + s * 4;
      int gr = block_row + r;
      float4 q = make_float4(0.f, 0.f, 0.f, 0.f);
      if (gr < n && k + 4 <= FIN) q = *(const float4*)(x + (size_t)gr * FIN + k);
      f16x4 p;
      p[0] = (f16)q.x; p[1] = (f16)q.y; p[2] = (f16)q.z; p[3] = (f16)q.w;
      *(f16x4*)&xs[r][s * 4] = p;
    }
    // stage W1T tile: f16 global -> f16 LDS, 16B chunks
    for (int i = t; i < HIDDIM * 8; i += 256) {
      int c = i >> 3, s = i & 7;
      f16x8 v = *(const f16x8*)(w1t + (size_t)c * KPAD + k0 + s * 8);
      *(f16x8*)&bt[c][s * 8] = v;
    }
    __syncthreads();
#pragma unroll
    for (int kk = 0; kk < 64; kk += 8) {
      f16x8 a8[4], b8[4];
#pragma unroll
      for (int i = 0; i < 4; ++i) a8[i] = *(const f16x8*)&xs[ty + 16 * i][kk];
#pragma unroll
      for (int j = 0; j < 4; ++j) b8[j] = *(const f16x8*)&bt[tx + 16 * j][kk];
#pragma unroll
      for (int i = 0; i < 4; ++i)
#pragma unroll
        for (int j = 0; j < 4; ++j) {
          float c = acc[i][j];
#pragma unroll
          for (int p = 0; p < 4; ++p) {
            f16x2 av; av[0] = a8[i][2 * p]; av[1] = a8[i][2 * p + 1];
            f16x2 bv; bv[0] = b8[j][2 * p]; bv[1] = b8[j][2 * p + 1];
            c = DOT2(av, bv, c);
          }
          acc[i][j] = c;
        }
    }
    __syncthreads();
  }
  // epilogue GEMM1: bias + relu -> hs
#pragma unroll
  for (int i = 0; i < 4; ++i)
#pragma unroll
    for (int j = 0; j < 4; ++j) {
      int r = ty + 16 * i, c = tx + 16 * j;
      float v = acc[i][j] + b1[c];
      hs[r][c] = v > 0.f ? v : 0.f;
    }
  for (int i = t; i < HIDDIM * NCLS; i += 256) w2s[i / NCLS][i % NCLS] = W2[i];
  __syncthreads();

  // GEMM2: 64 rows x 40 cols, f32
  int row = t >> 2, cg = (t & 3) * 10;
  float o[10] = {};
  for (int k = 0; k < HIDDIM; ++k) {
    float a = hs[row][k];
#pragma unroll
    for (int j = 0; j < 10; ++j) o[j] += a * w2s[k][cg + j];
  }
  int gr = block_row + row;
  if (gr < n) {
    float g0 = g[0];
    float* urow = u + (size_t)gr * NCLS + cg;
    float* orow = out + (size_t)gr * NCLS + cg;
#pragma unroll
    for (int j = 0; j < 10; ++j) {
      float val = o[j] + b2[cg + j];
      urow[j] = val;
      orow[j] = g0 * val;
    }
  }
}

// ---------------- SpMV step m: uout = D^-1/2 A D^-1/2 uin ; out += g[m]*uout ----------------
// Wave per node; lanes 0..39 own feature columns. Matches reference associativity:
// sum over edges of (dis[src]*uin[src]), then * dis[dst].
__global__ __launch_bounds__(256) void spmv_kernel(
    const int* __restrict__ col, const int* __restrict__ rowptr,
    const float* __restrict__ dis, const float* __restrict__ uin,
    float* __restrict__ uout, float* __restrict__ out, const float* __restrict__ g,
    const int* __restrict__ flags, int m) {
  if (flags[m] == 0) return;
  int wid = blockIdx.x * 4 + (threadIdx.x >> 6);
  int lane = threadIdx.x & 63;
  if (wid >= NNODES || lane >= NCLS) return;
  int lo = rowptr[wid], hi = rowptr[wid + 1];
  float acc = 0.f;
  for (int e = lo; e < hi; ++e) {
    int s = col[e];
    acc += dis[s] * uin[(size_t)s * NCLS + lane];
  }
  acc *= dis[wid];
  size_t idx = (size_t)wid * NCLS + lane;
  uout[idx] = acc;
  out[idx] += g[m] * acc;
}

// ---------------- log_softmax: one 64-lane wave per row ----------------
__global__ __launch_bounds__(256) void lsm_kernel(const float* __restrict__ out,
                                                  float* __restrict__ lsm, int n) {
  int wid = blockIdx.x * 4 + (threadIdx.x >> 6);
  int lane = threadIdx.x & 63;
  if (wid >= n) return;
  float xv = (lane < NCLS) ? out[(size_t)wid * NCLS + lane] : -INFINITY;
  float mx = xv;
#pragma unroll
  for (int off = 32; off; off >>= 1) mx = fmaxf(mx, __shfl_xor(mx, off));
  float e = (lane < NCLS) ? expf(xv - mx) : 0.f;
  float sum = e;
#pragma unroll
  for (int off = 32; off; off >>= 1) sum += __shfl_xor(sum, off);
  float lse = logf(sum);
  if (lane < NCLS) lsm[(size_t)wid * NCLS + lane] = xv - mx - lse;
}

extern "C" void kernel_launch(void* const* d_in, const int* in_sizes, int n_in,
                              void* d_out, int out_size, void* d_ws, size_t ws_size,
                              hipStream_t stream) {
  (void)n_in; (void)out_size; (void)ws_size;
  const float* x = (const float*)d_in[0];
  const int* ei = (const int*)d_in[1];
  const float* W1 = (const float*)d_in[2];
  const float* b1 = (const float*)d_in[3];
  const float* W2 = (const float*)d_in[4];
  const float* b2 = (const float*)d_in[5];
  const float* temp = (const float*)d_in[6];
  int E = in_sizes[1] / 2;
  const int* src = ei;
  const int* dst = ei + E;
  int n = NNODES;

  // ws layout in 4-byte words; total ~7.82M words (~31.3 MB)
  float* ws = (float*)d_ws;
  float* ua = ws;                          // 4,000,000 f32
  int* col = (int*)(ws + 4000000);         // 3,200,000 i32
  int* cnt_dst = (int*)(ws + 7200000);     // 100,000 i32 (memset covers this and next two)
  int* tmpc = (int*)(ws + 7300000);        // 100,000 i32
  int* deg_i = (int*)(ws + 7400000);       // 100,000 i32
  int* rowptr = (int*)(ws + 7500000);      // 100,001 i32
  float* dis = ws + 7600016;               // 100,000 f32
  float* g = ws + 7700016;                 // 16 f32
  int* flags = (int*)(ws + 7700032);       // 16 i32
  f16* w1t = (f16*)(ws + 7700048);         // 32,768 f16 = 16,384 words

  float* lsm = (float*)d_out;            // n*40, also ping-pong scratch during prop
  float* out = (float*)d_out + 4000000;  // n*40 accumulator, final output 1

  (void)hipMemsetAsync(cnt_dst, 0, 300000 * sizeof(int), stream);
  coeff_kernel<<<1, 64, 0, stream>>>(temp, g, flags);
  cnt_kernel<<<(E + 255) / 256, 256, 0, stream>>>(src, dst, deg_i, cnt_dst, flags, E);
  dis_kernel<<<(n + 255) / 256, 256, 0, stream>>>(deg_i, dis, flags, n);
  scan_kernel<<<1, 1024, 0, stream>>>(cnt_dst, rowptr, flags);
  fill_kernel<<<(E + 255) / 256, 256, 0, stream>>>(src, dst, rowptr, tmpc, col, flags, E);
  w1t_kernel<<<(HIDDIM * KPAD + 255) / 256, 256, 0, stream>>>(W1, w1t);
  mlp_kernel<<<(n + BM - 1) / BM, 256, 0, stream>>>(x, w1t, b1, W2, b2, g, ua, out, n);
  for (int m = 1; m <= KORD; ++m) {
    float* uin = (m & 1) ? ua : lsm;
    float* uout = (m & 1) ? lsm : ua;
    spmv_kernel<<<(n + 3) / 4, 256, 0, stream>>>(col, rowptr, dis, uin, uout, out, g,
                                                 flags, m);
  }
  lsm_kernel<<<(n + 3) / 4, 256, 0, stream>>>(out, lsm, n);
}

// Round 6
// 149.170 us; speedup vs baseline: 458.9866x; 1.6904x over previous
//
#include <hip/hip_runtime.h>
#include <hip/hip_bf16.h>
#include <math.h>

#define NNODES 100000
#define FIN 500
#define KPAD 512
#define HIDDIM 64
#define NCLS 40
#define KORD 10

typedef __bf16 bf16x8 __attribute__((ext_vector_type(8)));
typedef float f32x4 __attribute__((ext_vector_type(4)));

// ---------------- polynomial coefficients + need-flags from temp ----------------
// out = sum_j C(K,j)/2^K * relu(temp[j]) * (I-A)^j (I+A)^{K-j} h = sum_m g[m] A^m h
// g[m] = sum_j s_j * T[j][m], T[j][m] = coeff of x^m in (1-x)^j (1+x)^{K-j}.
// All intermediates are integers/1024 with numerators < 2^24, exact in f32.
// flags[m] = 1 iff any g[j] != 0 for j >= m  (SpMV step m still needed).
__global__ void coeff_kernel(const float* __restrict__ temp, float* __restrict__ g,
                             int* __restrict__ flags) {
  if (threadIdx.x != 0 || blockIdx.x != 0) return;
  float C[KORD + 1][KORD + 1];
  for (int n = 0; n <= KORD; ++n)
    for (int k = 0; k <= KORD; ++k) C[n][k] = 0.f;
  for (int n = 0; n <= KORD; ++n) {
    C[n][0] = 1.f;
    for (int k = 1; k <= n; ++k) C[n][k] = C[n - 1][k - 1] + C[n - 1][k];
  }
  float s[KORD + 1];
  for (int j = 0; j <= KORD; ++j) {
    float th = temp[j] > 0.f ? temp[j] : 0.f;
    s[j] = C[KORD][j] * (1.0f / 1024.0f) * th;
  }
  for (int m = 0; m <= KORD; ++m) {
    float acc = 0.f;
    for (int j = 0; j <= KORD; ++j) {
      float T = 0.f;
      for (int a = 0; a <= m; ++a) {
        int b = m - a;
        if (a <= j && b <= KORD - j)
          T += ((a & 1) ? -1.f : 1.f) * C[j][a] * C[KORD - j][b];
      }
      acc += s[j] * T;
    }
    g[m] = acc;
  }
  int any = 0;
  flags[0] = 1;
  for (int m = KORD; m >= 1; --m) {
    if (g[m] != 0.f) any = 1;
    flags[m] = any;
  }
}

// ---------------- counts: out-degree at src + in-degree at dst ----------------
__global__ __launch_bounds__(256) void cnt_kernel(const int* __restrict__ src,
                                                  const int* __restrict__ dst,
                                                  int* __restrict__ deg_i,
                                                  int* __restrict__ cnt_dst,
                                                  const int* __restrict__ flags, int E) {
  if (flags[1] == 0) return;
  for (int e = blockIdx.x * 256 + threadIdx.x; e < E; e += gridDim.x * 256) {
    atomicAdd(&deg_i[src[e]], 1);
    atomicAdd(&cnt_dst[dst[e]], 1);
  }
}

__global__ __launch_bounds__(256) void dis_kernel(const int* __restrict__ deg_i,
                                                  float* __restrict__ dis,
                                                  const int* __restrict__ flags, int n) {
  if (flags[1] == 0) return;
  for (int i = blockIdx.x * 256 + threadIdx.x; i < n; i += gridDim.x * 256) {
    int d = deg_i[i];
    dis[i] = d > 0 ? 1.0f / sqrtf((float)d) : 0.f;
  }
}

// ---------------- exclusive prefix sum of cnt_dst -> rowptr[0..n] ----------------
__global__ __launch_bounds__(1024) void scan_kernel(const int* __restrict__ cnt,
                                                    int* __restrict__ rowptr,
                                                    const int* __restrict__ flags) {
  if (flags[1] == 0) return;
  __shared__ int part[1024];
  int t = threadIdx.x;
  const int chunk = (NNODES + 1023) / 1024;
  int lo = t * chunk, hi = lo + chunk;
  if (hi > NNODES) hi = NNODES;
  int s = 0;
  for (int i = lo; i < hi; ++i) s += cnt[i];
  part[t] = s;
  __syncthreads();
  for (int off = 1; off < 1024; off <<= 1) {
    int v = (t >= off) ? part[t - off] : 0;
    __syncthreads();
    part[t] += v;
    __syncthreads();
  }
  int run = (t > 0) ? part[t - 1] : 0;
  for (int i = lo; i < hi; ++i) {
    rowptr[i] = run;
    run += cnt[i];
  }
  if (t == 1023) rowptr[NNODES] = run;
}

// ---------------- CSR fill (dst-major): col[pos] = src ----------------
__global__ __launch_bounds__(256) void fill_kernel(const int* __restrict__ src,
                                                   const int* __restrict__ dst,
                                                   const int* __restrict__ rowptr,
                                                   int* __restrict__ tmpc,
                                                   int* __restrict__ col,
                                                   const int* __restrict__ flags, int E) {
  if (flags[1] == 0) return;
  for (int e = blockIdx.x * 256 + threadIdx.x; e < E; e += gridDim.x * 256) {
    int d = dst[e];
    int pos = rowptr[d] + atomicAdd(&tmpc[d], 1);
    col[pos] = src[e];
  }
}

// ---------------- W1 -> transposed bf16, K padded to 512: w1t[c][k] ----------------
__global__ __launch_bounds__(256) void w1t_kernel(const float* __restrict__ W1,
                                                  __bf16* __restrict__ w1t) {
  int idx = blockIdx.x * 256 + threadIdx.x;
  if (idx >= HIDDIM * KPAD) return;
  int c = idx >> 9, k = idx & (KPAD - 1);
  float v = (k < FIN) ? W1[(size_t)k * HIDDIM + c] : 0.f;
  w1t[(size_t)c * KPAD + k] = (__bf16)v;
}

// ---------------- fused MLP: u = relu(x@W1+b1)@W2+b2 ; out = g0*u ----------------
// GEMM1: bf16 MFMA 16x16x32. x staged f32 -> LDS via global_load_lds (width 16),
// source-side XOR swizzle (slot u holds logical unit u^(r&7)) so fragment reads
// (16 rows x same k) hit 8 distinct 16B slots -> <=2-way bank conflict (free).
// Each wave owns one 16-col tile of HID; B-frags from global w1t (bf16), 4/chunk.
__global__ __launch_bounds__(256, 4) void mlp_kernel(
    const float* __restrict__ x, const __bf16* __restrict__ w1t,
    const float* __restrict__ b1, const float* __restrict__ W2,
    const float* __restrict__ b2, const float* __restrict__ g,
    float* __restrict__ u, float* __restrict__ out, int n) {
  __shared__ __align__(16) char arena[32768];  // x chunk [64 rows][512 B]; later hs+w2s

  const int t = threadIdx.x;
  const int w = t >> 6;      // wave id = col-tile
  const int lane = t & 63;
  const int row0 = blockIdx.x * 64;

  // ---- staging helper: chunk c covers k = c*128 .. c*128+127 (f32) ----
  // call i of wave w fills LDS bytes [(w*8+i)*1024, +1024): 2 rows of 512 B.
  // per-lane: r = (w*8+i)*2 + (lane>>5), slot = lane&31, logical = slot^(r&7).
#define STAGE_CHUNK(c_)                                                         \
  {                                                                             \
    _Pragma("unroll") for (int i = 0; i < 8; ++i) {                             \
      int r = (w * 8 + i) * 2 + (lane >> 5);                                    \
      int ulog = (lane & 31) ^ (r & 7);                                         \
      if ((c_) == 3) ulog = ulog > 28 ? 28 : ulog;  /* k>=500 -> B is 0 */      \
      int gr = row0 + r;                                                        \
      if (gr > NNODES - 1) gr = NNODES - 1;                                     \
      const float* gp = x + (size_t)gr * FIN + (c_) * 128 + ulog * 4;           \
      __builtin_amdgcn_global_load_lds(                                         \
          (const __attribute__((address_space(1))) void*)gp,                    \
          (__attribute__((address_space(3))) void*)(arena + (w * 8 + i) * 1024),\
          16, 0, 0);                                                            \
    }                                                                           \
  }

  const int bcol = w * 16 + (lane & 15);  // this lane's B column (= output col)
  const int koff = (lane >> 4) * 8;       // k offset within 32-k tile

  f32x4 acc[4] = {};
  bf16x8 bfr[4];

  STAGE_CHUNK(0);
#pragma unroll
  for (int kt = 0; kt < 4; ++kt)
    bfr[kt] = *(const bf16x8*)(w1t + (size_t)bcol * KPAD + kt * 32 + koff);

  for (int c = 0; c < 4; ++c) {
    __syncthreads();  // stage(c) complete (barrier drains vmcnt)
#pragma unroll
    for (int kt = 0; kt < 4; ++kt) {
      int ub = kt * 8 + (lane >> 4) * 2;  // first 16B unit of this frag
#pragma unroll
      for (int rt = 0; rt < 4; ++rt) {
        int r = rt * 16 + (lane & 15);
        const float4 q0 = *(const float4*)(arena + r * 512 + ((ub ^ (r & 7)) << 4));
        const float4 q1 =
            *(const float4*)(arena + r * 512 + (((ub + 1) ^ (r & 7)) << 4));
        bf16x8 a;
        a[0] = (__bf16)q0.x; a[1] = (__bf16)q0.y; a[2] = (__bf16)q0.z; a[3] = (__bf16)q0.w;
        a[4] = (__bf16)q1.x; a[5] = (__bf16)q1.y; a[6] = (__bf16)q1.z; a[7] = (__bf16)q1.w;
        acc[rt] = __builtin_amdgcn_mfma_f32_16x16x32_bf16(a, bfr[kt], acc[rt], 0, 0, 0);
      }
    }
    __syncthreads();  // all reads of chunk c done
    if (c < 3) {
      STAGE_CHUNK(c + 1);
#pragma unroll
      for (int kt = 0; kt < 4; ++kt)
        bfr[kt] = *(const bf16x8*)(w1t + (size_t)bcol * KPAD + (c + 1) * 128 +
                                   kt * 32 + koff);
    }
  }

  // ---- epilogue: hs = relu(acc + b1) in LDS (arena reused), then GEMM2 f32 ----
  float* hs = (float*)arena;              // [64][65]
  float* w2s = (float*)(arena + 16640);   // [64][40] = W2 copy
  {
    float bv = b1[bcol];
#pragma unroll
    for (int rt = 0; rt < 4; ++rt)
#pragma unroll
      for (int reg = 0; reg < 4; ++reg) {
        int rrow = rt * 16 + (lane >> 4) * 4 + reg;
        float v = acc[rt][reg] + bv;
        hs[rrow * 65 + bcol] = v > 0.f ? v : 0.f;
      }
  }
  for (int i = t; i < HIDDIM * NCLS; i += 256) w2s[i] = W2[i];
  __syncthreads();

  int row = t >> 2, cg = (t & 3) * 10;
  float o[10] = {};
  for (int k = 0; k < HIDDIM; ++k) {
    float a = hs[row * 65 + k];
#pragma unroll
    for (int j = 0; j < 10; ++j) o[j] += a * w2s[k * 40 + cg + j];
  }
  int gr = row0 + row;
  if (gr < n) {
    float g0 = g[0];
    float* urow = u + (size_t)gr * NCLS + cg;
    float* orow = out + (size_t)gr * NCLS + cg;
#pragma unroll
    for (int j = 0; j < 10; ++j) {
      float val = o[j] + b2[cg + j];
      urow[j] = val;
      orow[j] = g0 * val;
    }
  }
#undef STAGE_CHUNK
}

// ---------------- SpMV step m: uout = D^-1/2 A D^-1/2 uin ; out += g[m]*uout ----------------
// Wave per node (grid-stride); lanes 0..39 own feature columns. Matches reference
// associativity: sum over edges of (dis[src]*uin[src]), then * dis[dst].
__global__ __launch_bounds__(256) void spmv_kernel(
    const int* __restrict__ col, const int* __restrict__ rowptr,
    const float* __restrict__ dis, const float* __restrict__ uin,
    float* __restrict__ uout, float* __restrict__ out, const float* __restrict__ g,
    const int* __restrict__ flags, int m) {
  if (flags[m] == 0) return;
  int lane = threadIdx.x & 63;
  if (lane >= NCLS) return;
  int stride = gridDim.x * 4;
  for (int wid = blockIdx.x * 4 + (threadIdx.x >> 6); wid < NNODES; wid += stride) {
    int lo = rowptr[wid], hi = rowptr[wid + 1];
    float acc = 0.f;
    for (int e = lo; e < hi; ++e) {
      int s = col[e];
      acc += dis[s] * uin[(size_t)s * NCLS + lane];
    }
    acc *= dis[wid];
    size_t idx = (size_t)wid * NCLS + lane;
    uout[idx] = acc;
    out[idx] += g[m] * acc;
  }
}

// ---------------- log_softmax: one 64-lane wave per row (grid-stride) ----------------
__global__ __launch_bounds__(256) void lsm_kernel(const float* __restrict__ out,
                                                  float* __restrict__ lsm, int n) {
  int lane = threadIdx.x & 63;
  int stride = gridDim.x * 4;
  for (int wid = blockIdx.x * 4 + (threadIdx.x >> 6); wid < n; wid += stride) {
    float xv = (lane < NCLS) ? out[(size_t)wid * NCLS + lane] : -INFINITY;
    float mx = xv;
#pragma unroll
    for (int off = 32; off; off >>= 1) mx = fmaxf(mx, __shfl_xor(mx, off));
    float e = (lane < NCLS) ? expf(xv - mx) : 0.f;
    float sum = e;
#pragma unroll
    for (int off = 32; off; off >>= 1) sum += __shfl_xor(sum, off);
    float lse = logf(sum);
    if (lane < NCLS) lsm[(size_t)wid * NCLS + lane] = xv - mx - lse;
  }
}

extern "C" void kernel_launch(void* const* d_in, const int* in_sizes, int n_in,
                              void* d_out, int out_size, void* d_ws, size_t ws_size,
                              hipStream_t stream) {
  (void)n_in; (void)out_size; (void)ws_size;
  const float* x = (const float*)d_in[0];
  const int* ei = (const int*)d_in[1];
  const float* W1 = (const float*)d_in[2];
  const float* b1 = (const float*)d_in[3];
  const float* W2 = (const float*)d_in[4];
  const float* b2 = (const float*)d_in[5];
  const float* temp = (const float*)d_in[6];
  int E = in_sizes[1] / 2;
  const int* src = ei;
  const int* dst = ei + E;
  int n = NNODES;

  // ws layout in 4-byte words; total ~7.72M words (~30.9 MB)
  float* ws = (float*)d_ws;
  float* ua = ws;                          // 4,000,000 f32
  int* col = (int*)(ws + 4000000);         // 3,200,000 i32
  int* cnt_dst = (int*)(ws + 7200000);     // 100,000 i32 (memset covers this and next two)
  int* tmpc = (int*)(ws + 7300000);        // 100,000 i32
  int* deg_i = (int*)(ws + 7400000);       // 100,000 i32
  int* rowptr = (int*)(ws + 7500000);      // 100,001 i32
  float* dis = ws + 7600016;               // 100,000 f32
  float* g = ws + 7700016;                 // 16 f32
  int* flags = (int*)(ws + 7700032);       // 16 i32
  __bf16* w1t = (__bf16*)(ws + 7700048);   // 32,768 bf16 = 16,384 words

  float* lsm = (float*)d_out;            // n*40, also ping-pong scratch during prop
  float* out = (float*)d_out + 4000000;  // n*40 accumulator, final output 1

  (void)hipMemsetAsync(cnt_dst, 0, 300000 * sizeof(int), stream);
  coeff_kernel<<<1, 64, 0, stream>>>(temp, g, flags);
  cnt_kernel<<<1024, 256, 0, stream>>>(src, dst, deg_i, cnt_dst, flags, E);
  dis_kernel<<<512, 256, 0, stream>>>(deg_i, dis, flags, n);
  scan_kernel<<<1, 1024, 0, stream>>>(cnt_dst, rowptr, flags);
  fill_kernel<<<1024, 256, 0, stream>>>(src, dst, rowptr, tmpc, col, flags, E);
  w1t_kernel<<<(HIDDIM * KPAD + 255) / 256, 256, 0, stream>>>(W1, w1t);
  mlp_kernel<<<(n + 63) / 64, 256, 0, stream>>>(x, w1t, b1, W2, b2, g, ua, out, n);
  for (int m = 1; m <= KORD; ++m) {
    float* uin = (m & 1) ? ua : lsm;
    float* uout = (m & 1) ? lsm : ua;
    spmv_kernel<<<1024, 256, 0, stream>>>(col, rowptr, dis, uin, uout, out, g, flags, m);
  }
  lsm_kernel<<<2048, 256, 0, stream>>>(out, lsm, n);
}